// Round 1
// baseline (600.867 us; speedup 1.0000x reference)
//
#include <hip/hip_runtime.h>

typedef _Float16 f16;
typedef f16 f16x8 __attribute__((ext_vector_type(8)));
typedef float f32x4 __attribute__((ext_vector_type(4)));

#define EPSBN 1e-3f

enum { EPI_ATT = 0, EPI_PROJ = 1, EPI_GLU = 2, EPI_OUT = 3 };

// ---------------- prep: fold BN into weights, transpose to [N][K] f16 ----------------
__global__ __launch_bounds__(256) void prep_kernel(
    const float* __restrict__ att_w, const float* __restrict__ att_gamma,
    const float* __restrict__ att_beta, const float* __restrict__ att_mean,
    const float* __restrict__ att_var,
    const float* __restrict__ proj_w,
    const float* __restrict__ glu_w, const float* __restrict__ glu_gamma,
    const float* __restrict__ glu_beta, const float* __restrict__ glu_mean,
    const float* __restrict__ glu_var,
    const float* __restrict__ out_w,
    f16* __restrict__ watt, f16* __restrict__ wproj, f16* __restrict__ wglu,
    f16* __restrict__ wout, float* __restrict__ t_att, float* __restrict__ t_glu)
{
    int tid = blockIdx.x * blockDim.x + threadIdx.x;
    int nth = gridDim.x * blockDim.x;
    // att_w [512][512] -> watt [n][k], scale folded
    for (int i = tid; i < 512 * 512; i += nth) {
        int n = i >> 9, k = i & 511;
        float s = att_gamma[n] * rsqrtf(att_var[n] + EPSBN);
        watt[i] = (f16)(att_w[k * 512 + n] * s);
    }
    // proj_w [512][256] -> wproj [n=256][k=512]
    for (int i = tid; i < 256 * 512; i += nth) {
        int n = i >> 9, k = i & 511;
        wproj[i] = (f16)(proj_w[k * 256 + n]);
    }
    // glu_w [4][256][512] -> wglu [g][n=512 interleaved val/gate][k=256]
    for (int i = tid; i < 4 * 512 * 256; i += nth) {
        int g = i >> 17, r = i & 131071;
        int n = r >> 8, k = r & 255;
        int c = (n & 1) ? 256 + (n >> 1) : (n >> 1);
        float s = glu_gamma[g * 512 + c] * rsqrtf(glu_var[g * 512 + c] + EPSBN);
        wglu[i] = (f16)(glu_w[g * 131072 + k * 512 + c] * s);
    }
    // out_w [256][128] -> wout [n=128][k=256]
    for (int i = tid; i < 128 * 256; i += nth) {
        int n = i >> 8, k = i & 255;
        wout[i] = (f16)(out_w[k * 128 + n]);
    }
    for (int n = tid; n < 512; n += nth) {
        float s = att_gamma[n] * rsqrtf(att_var[n] + EPSBN);
        t_att[n] = att_beta[n] - att_mean[n] * s;
    }
    for (int i = tid; i < 4 * 512; i += nth) {
        int g = i >> 9, n = i & 511;
        int c = (n & 1) ? 256 + (n >> 1) : (n >> 1);
        float s = glu_gamma[g * 512 + c] * rsqrtf(glu_var[g * 512 + c] + EPSBN);
        t_glu[i] = glu_beta[g * 512 + c] - glu_mean[g * 512 + c] * s;
    }
}

// ---------------- generic 128x128 MFMA GEMM with fused epilogues ----------------
// A [M][K] (f32 or f16), Bt [N][K] f16 (pre-transposed). C tile = 128x128.
template <int K, int EPI, bool AF32>
__global__ __launch_bounds__(256) void gemm_kernel(
    const float* __restrict__ Af32, const f16* __restrict__ Af16,
    const f16* __restrict__ Bt, const float* __restrict__ tb,
    const float* __restrict__ priors, const f16* __restrict__ xold,
    float* __restrict__ outF, f16* __restrict__ outH)
{
    constexpr int PAD = 40;  // f16 row stride: 80B = 20 banks -> 2-way (free)
    __shared__ f16 Alds[128 * PAD];
    __shared__ f16 Blds[128 * PAD];
    const int rBase = blockIdx.x * 128;
    const int cBase = blockIdx.y * 128;
    const int lane = threadIdx.x & 63;
    const int w = threadIdx.x >> 6;
    const int wr = w & 1, wc = w >> 1;
    const int lrow = lane & 15, lq = lane >> 4;
    const int sr = threadIdx.x >> 2;
    const int sc = (threadIdx.x & 3) * 8;

    f32x4 acc[4][4];
#pragma unroll
    for (int m = 0; m < 4; m++)
#pragma unroll
        for (int n = 0; n < 4; n++) acc[m][n] = (f32x4){0.f, 0.f, 0.f, 0.f};

    for (int k0 = 0; k0 < K; k0 += 32) {
        f16x8 a0, a1, b0, b1;
        if constexpr (AF32) {
            const float* p0 = Af32 + (size_t)(rBase + sr) * K + k0 + sc;
            const float* p1 = p0 + (size_t)64 * K;
            float4 u0 = *(const float4*)p0, u1 = *(const float4*)(p0 + 4);
            float4 v0 = *(const float4*)p1, v1 = *(const float4*)(p1 + 4);
            a0 = (f16x8){(f16)u0.x, (f16)u0.y, (f16)u0.z, (f16)u0.w,
                         (f16)u1.x, (f16)u1.y, (f16)u1.z, (f16)u1.w};
            a1 = (f16x8){(f16)v0.x, (f16)v0.y, (f16)v0.z, (f16)v0.w,
                         (f16)v1.x, (f16)v1.y, (f16)v1.z, (f16)v1.w};
        } else {
            a0 = *(const f16x8*)(Af16 + (size_t)(rBase + sr) * K + k0 + sc);
            a1 = *(const f16x8*)(Af16 + (size_t)(rBase + sr + 64) * K + k0 + sc);
        }
        b0 = *(const f16x8*)(Bt + (size_t)(cBase + sr) * K + k0 + sc);
        b1 = *(const f16x8*)(Bt + (size_t)(cBase + sr + 64) * K + k0 + sc);
        __syncthreads();  // previous iteration's ds_reads done
        *(f16x8*)&Alds[sr * PAD + sc] = a0;
        *(f16x8*)&Alds[(sr + 64) * PAD + sc] = a1;
        *(f16x8*)&Blds[sr * PAD + sc] = b0;
        *(f16x8*)&Blds[(sr + 64) * PAD + sc] = b1;
        __syncthreads();
        f16x8 af[4], bf[4];
#pragma unroll
        for (int m = 0; m < 4; m++)
            af[m] = *(const f16x8*)&Alds[(wr * 64 + m * 16 + lrow) * PAD + lq * 8];
#pragma unroll
        for (int n = 0; n < 4; n++)
            bf[n] = *(const f16x8*)&Blds[(wc * 64 + n * 16 + lrow) * PAD + lq * 8];
#pragma unroll
        for (int m = 0; m < 4; m++)
#pragma unroll
            for (int n = 0; n < 4; n++)
                acc[m][n] = __builtin_amdgcn_mfma_f32_16x16x32_f16(af[m], bf[n], acc[m][n], 0, 0, 0);
    }

    // epilogue: C frag layout col=lane&15, row=(lane>>4)*4+j
#pragma unroll
    for (int m = 0; m < 4; m++) {
#pragma unroll
        for (int n = 0; n < 4; n++) {
            const int Rb = rBase + wr * 64 + m * 16 + lq * 4;
            const int Cc = cBase + wc * 64 + n * 16 + lrow;
#pragma unroll
            for (int j = 0; j < 4; j++) {
                const int R = Rb + j;
                float v = acc[m][n][j] + tb[Cc];
                if constexpr (EPI == EPI_ATT) {
                    const size_t id = (size_t)R * 512 + Cc;
                    outF[id] = v * priors[id];
                } else if constexpr (EPI == EPI_PROJ) {
                    outH[(size_t)R * 256 + Cc] = (f16)v;
                } else if constexpr (EPI == EPI_GLU) {
                    float o = __shfl_xor(v, 1, 64);  // pair val<->gate (interleaved cols)
                    if (!(lane & 1)) {
                        const int xi = Cc >> 1;
                        const size_t id = (size_t)R * 256 + xi;
                        float xn = v * (1.f / (1.f + __expf(-o)));
                        outH[id] = (f16)(xn + (float)xold[id]);
                    }
                } else {  // EPI_OUT
                    outF[(size_t)R * 128 + Cc] = v;
                }
            }
        }
    }
}

// ---------------- sparsemax: one wave per row of 512, bisection + exact tau ----------------
__global__ __launch_bounds__(256) void sparsemax_kernel(
    const float* __restrict__ zin, const float* __restrict__ priors,
    const float* __restrict__ inputs, float* __restrict__ maskout,
    float* __restrict__ npout, f16* __restrict__ masked)
{
    const int w = threadIdx.x >> 6, lane = threadIdx.x & 63;
    const int row = blockIdx.x * 4 + w;
    const size_t base = (size_t)row * 512 + lane * 8;
    float z[8];
    {
        float4 u0 = *(const float4*)(zin + base);
        float4 u1 = *(const float4*)(zin + base + 4);
        z[0] = u0.x; z[1] = u0.y; z[2] = u0.z; z[3] = u0.w;
        z[4] = u1.x; z[5] = u1.y; z[6] = u1.z; z[7] = u1.w;
    }
    float mx = z[0];
#pragma unroll
    for (int j = 1; j < 8; j++) mx = fmaxf(mx, z[j]);
#pragma unroll
    for (int d = 1; d < 64; d <<= 1) mx = fmaxf(mx, __shfl_xor(mx, d, 64));
    float lo = mx - 1.f, hi = mx;
    for (int it = 0; it < 24; ++it) {
        float tau = 0.5f * (lo + hi);
        float s = 0.f;
#pragma unroll
        for (int j = 0; j < 8; j++) s += fmaxf(z[j] - tau, 0.f);
#pragma unroll
        for (int d = 1; d < 64; d <<= 1) s += __shfl_xor(s, d, 64);
        if (s >= 1.f) lo = tau; else hi = tau;
    }
    float cnt = 0.f, sm = 0.f;
#pragma unroll
    for (int j = 0; j < 8; j++) {
        if (z[j] > lo) { cnt += 1.f; sm += z[j]; }
    }
#pragma unroll
    for (int d = 1; d < 64; d <<= 1) {
        cnt += __shfl_xor(cnt, d, 64);
        sm += __shfl_xor(sm, d, 64);
    }
    const float tau = (sm - 1.f) / cnt;
    float4 p0 = *(const float4*)(priors + base);
    float4 p1 = *(const float4*)(priors + base + 4);
    float4 x0 = *(const float4*)(inputs + base);
    float4 x1 = *(const float4*)(inputs + base + 4);
    float mk[8];
#pragma unroll
    for (int j = 0; j < 8; j++) mk[j] = fmaxf(z[j] - tau, 0.f);
    float4 m0 = {mk[0], mk[1], mk[2], mk[3]}, m1 = {mk[4], mk[5], mk[6], mk[7]};
    *(float4*)(maskout + base) = m0;
    *(float4*)(maskout + base + 4) = m1;
    float4 n0 = {p0.x * (1.f - mk[0]), p0.y * (1.f - mk[1]), p0.z * (1.f - mk[2]), p0.w * (1.f - mk[3])};
    float4 n1 = {p1.x * (1.f - mk[4]), p1.y * (1.f - mk[5]), p1.z * (1.f - mk[6]), p1.w * (1.f - mk[7])};
    *(float4*)(npout + base) = n0;
    *(float4*)(npout + base + 4) = n1;
    f16x8 mm;
    mm[0] = (f16)(mk[0] * x0.x); mm[1] = (f16)(mk[1] * x0.y);
    mm[2] = (f16)(mk[2] * x0.z); mm[3] = (f16)(mk[3] * x0.w);
    mm[4] = (f16)(mk[4] * x1.x); mm[5] = (f16)(mk[5] * x1.y);
    mm[6] = (f16)(mk[6] * x1.z); mm[7] = (f16)(mk[7] * x1.w);
    *(f16x8*)(masked + base) = mm;
}

extern "C" void kernel_launch(void* const* d_in, const int* in_sizes, int n_in,
                              void* d_out, int out_size, void* d_ws, size_t ws_size,
                              hipStream_t stream)
{
    const float* inputs    = (const float*)d_in[0];
    const float* priors    = (const float*)d_in[1];
    const float* att_w     = (const float*)d_in[2];
    const float* att_gamma = (const float*)d_in[3];
    const float* att_beta  = (const float*)d_in[4];
    const float* att_mean  = (const float*)d_in[5];
    const float* att_var   = (const float*)d_in[6];
    const float* proj_w    = (const float*)d_in[7];
    const float* proj_b    = (const float*)d_in[8];
    const float* glu_w     = (const float*)d_in[9];
    const float* glu_gamma = (const float*)d_in[10];
    const float* glu_beta  = (const float*)d_in[11];
    const float* glu_mean  = (const float*)d_in[12];
    const float* glu_var   = (const float*)d_in[13];
    const float* out_w     = (const float*)d_in[14];
    const float* out_b     = (const float*)d_in[15];

    char* ws = (char*)d_ws;
    f16*   watt   = (f16*)(ws + 0);          // 512*512 f16
    f16*   wproj  = (f16*)(ws + 524288);     // 256*512
    f16*   wglu   = (f16*)(ws + 786432);     // 4*512*256
    f16*   wout   = (f16*)(ws + 1835008);    // 128*256
    float* t_att  = (float*)(ws + 1900544);  // 512
    float* t_glu  = (float*)(ws + 1902592);  // 4*512
    f16*   masked = (f16*)(ws + 1910784);    // 65536*512 f16
    f16*   x0     = (f16*)(ws + 69019648);   // 65536*256 f16
    f16*   x1     = (f16*)(ws + 102574080);  // 65536*256 f16

    float* outp  = (float*)d_out;
    float* maskp = outp + (size_t)65536 * 128;
    float* npp   = maskp + (size_t)65536 * 512;

    prep_kernel<<<512, 256, 0, stream>>>(att_w, att_gamma, att_beta, att_mean, att_var,
                                         proj_w, glu_w, glu_gamma, glu_beta, glu_mean,
                                         glu_var, out_w, watt, wproj, wglu, wout, t_att, t_glu);

    // z = bn(inputs@att_w)*priors  -> stored temporarily in mask region of d_out
    gemm_kernel<512, EPI_ATT, true><<<dim3(512, 4), 256, 0, stream>>>(
        inputs, nullptr, watt, t_att, priors, nullptr, maskp, nullptr);

    sparsemax_kernel<<<16384, 256, 0, stream>>>(maskp, priors, inputs, maskp, npp, masked);

    // x0 = masked @ proj_w + b
    gemm_kernel<512, EPI_PROJ, false><<<dim3(512, 2), 256, 0, stream>>>(
        nullptr, masked, wproj, proj_b, nullptr, nullptr, nullptr, x0);

    // 4 GLU blocks (interleaved val/gate weights), x ping-pong
    gemm_kernel<256, EPI_GLU, false><<<dim3(512, 4), 256, 0, stream>>>(
        nullptr, x0, wglu, t_glu, nullptr, x0, nullptr, x1);
    gemm_kernel<256, EPI_GLU, false><<<dim3(512, 4), 256, 0, stream>>>(
        nullptr, x1, wglu + 131072, t_glu + 512, nullptr, x1, nullptr, x0);
    gemm_kernel<256, EPI_GLU, false><<<dim3(512, 4), 256, 0, stream>>>(
        nullptr, x0, wglu + 262144, t_glu + 1024, nullptr, x0, nullptr, x1);
    gemm_kernel<256, EPI_GLU, false><<<dim3(512, 4), 256, 0, stream>>>(
        nullptr, x1, wglu + 393216, t_glu + 1536, nullptr, x1, nullptr, x0);

    // output = x @ out_w + b
    gemm_kernel<256, EPI_OUT, false><<<dim3(512, 1), 256, 0, stream>>>(
        nullptr, x0, wout, out_b, nullptr, nullptr, outp, nullptr);
}

// Round 3
// 491.888 us; speedup vs baseline: 1.2216x; 1.2216x over previous
//
#include <hip/hip_runtime.h>

typedef _Float16 f16;
typedef f16 f16x8 __attribute__((ext_vector_type(8)));
typedef float f32x4 __attribute__((ext_vector_type(4)));

#define EPSBN 1e-3f

enum { EPI_ATT = 0, EPI_PROJ = 1, EPI_GLU = 2, EPI_OUT = 3 };

// async global->LDS, 16B per lane; lds dest must be wave-uniform base (+lane*16 by HW)
__device__ __forceinline__ void stage16(const f16* g, const f16* l) {
    __builtin_amdgcn_global_load_lds(
        (const __attribute__((address_space(1))) unsigned int*)g,
        (__attribute__((address_space(3))) unsigned int*)l,
        16, 0, 0);
}

// ---------------- prep: fold BN into weights, transpose to [N][K] f16, cvt inputs ----------------
__global__ __launch_bounds__(256) void prep_kernel(
    const float* __restrict__ inputs,
    const float* __restrict__ att_w, const float* __restrict__ att_gamma,
    const float* __restrict__ att_beta, const float* __restrict__ att_mean,
    const float* __restrict__ att_var,
    const float* __restrict__ proj_w,
    const float* __restrict__ glu_w, const float* __restrict__ glu_gamma,
    const float* __restrict__ glu_beta, const float* __restrict__ glu_mean,
    const float* __restrict__ glu_var,
    const float* __restrict__ out_w,
    f16* __restrict__ inputs16,
    f16* __restrict__ watt, f16* __restrict__ wproj, f16* __restrict__ wglu,
    f16* __restrict__ wout, float* __restrict__ t_att, float* __restrict__ t_glu)
{
    int tid = blockIdx.x * blockDim.x + threadIdx.x;
    int nth = gridDim.x * blockDim.x;
    // inputs f32 -> f16, vectorized
    for (int i = tid; i < 65536 * 512 / 8; i += nth) {
        float4 u0 = ((const float4*)inputs)[i * 2];
        float4 u1 = ((const float4*)inputs)[i * 2 + 1];
        f16x8 h = {(f16)u0.x, (f16)u0.y, (f16)u0.z, (f16)u0.w,
                   (f16)u1.x, (f16)u1.y, (f16)u1.z, (f16)u1.w};
        ((f16x8*)inputs16)[i] = h;
    }
    // att_w [512][512] -> watt [n][k], BN scale folded
    for (int i = tid; i < 512 * 512; i += nth) {
        int n = i >> 9, k = i & 511;
        float s = att_gamma[n] * rsqrtf(att_var[n] + EPSBN);
        watt[i] = (f16)(att_w[k * 512 + n] * s);
    }
    // proj_w [512][256] -> wproj [n=256][k=512]
    for (int i = tid; i < 256 * 512; i += nth) {
        int n = i >> 9, k = i & 511;
        wproj[i] = (f16)(proj_w[k * 256 + n]);
    }
    // glu_w [4][256][512] -> wglu [g][n=512 interleaved val/gate][k=256]
    for (int i = tid; i < 4 * 512 * 256; i += nth) {
        int g = i >> 17, r = i & 131071;
        int n = r >> 8, k = r & 255;
        int c = (n & 1) ? 256 + (n >> 1) : (n >> 1);
        float s = glu_gamma[g * 512 + c] * rsqrtf(glu_var[g * 512 + c] + EPSBN);
        wglu[i] = (f16)(glu_w[g * 131072 + k * 512 + c] * s);
    }
    // out_w [256][128] -> wout [n=128][k=256]
    for (int i = tid; i < 128 * 256; i += nth) {
        int n = i >> 8, k = i & 255;
        wout[i] = (f16)(out_w[k * 128 + n]);
    }
    for (int n = tid; n < 512; n += nth) {
        float s = att_gamma[n] * rsqrtf(att_var[n] + EPSBN);
        t_att[n] = att_beta[n] - att_mean[n] * s;
    }
    for (int i = tid; i < 4 * 512; i += nth) {
        int g = i >> 9, n = i & 511;
        int c = (n & 1) ? 256 + (n >> 1) : (n >> 1);
        float s = glu_gamma[g * 512 + c] * rsqrtf(glu_var[g * 512 + c] + EPSBN);
        t_glu[i] = glu_beta[g * 512 + c] - glu_mean[g * 512 + c] * s;
    }
}

// ---------------- m97-style 128x128 MFMA GEMM, global_load_lds staging ----------------
// A [M][K] f16, Bt [N][K] f16. 4 waves, wave tile 64x64, BK=32, linear LDS.
template <int K, int NBLK, int EPI>
__global__ __launch_bounds__(256) void gemm_kernel(
    const f16* __restrict__ A, const f16* __restrict__ Bt,
    const float* __restrict__ tb, const f16* __restrict__ xold,
    float* __restrict__ outF, f16* __restrict__ outH)
{
    __shared__ f16 Alds[128 * 32];
    __shared__ f16 Blds[128 * 32];
    // XCD-aware swizzle (nwg is always a multiple of 8 here)
    int wg = blockIdx.x;
    const int chunk = gridDim.x >> 3;
    wg = (wg & 7) * chunk + (wg >> 3);
    const int rBase = (wg / NBLK) * 128;
    const int cBase = (wg % NBLK) * 128;
    const int tid = threadIdx.x;
    const int lane = tid & 63;
    const int w = tid >> 6;
    const int wr = w & 1, wc = w >> 1;
    const int lr = lane & 15, lq = lane >> 4;

    f32x4 acc[4][4];
#pragma unroll
    for (int m = 0; m < 4; m++)
#pragma unroll
        for (int n = 0; n < 4; n++) acc[m][n] = (f32x4){0.f, 0.f, 0.f, 0.f};

    for (int k0 = 0; k0 < K; k0 += 32) {
        __syncthreads();  // previous iteration's ds_reads complete
#pragma unroll
        for (int i = 0; i < 2; i++) {
            // 16B chunk index c over linear [128][32] f16 tile: row = c>>2, col = (c&3)*8
            const int c = i * 256 + tid;
            stage16(A + (size_t)(rBase + (c >> 2)) * K + k0 + (c & 3) * 8,
                    (const f16*)((const char*)Alds + (i * 256 + (w << 6)) * 16));
            stage16(Bt + (size_t)(cBase + (c >> 2)) * K + k0 + (c & 3) * 8,
                    (const f16*)((const char*)Blds + (i * 256 + (w << 6)) * 16));
        }
        __syncthreads();  // staging complete (compiler drains vmcnt before barrier)
        f16x8 af[4], bf[4];
#pragma unroll
        for (int m = 0; m < 4; m++)
            af[m] = *(const f16x8*)&Alds[(wr * 64 + m * 16 + lr) * 32 + lq * 8];
#pragma unroll
        for (int n = 0; n < 4; n++)
            bf[n] = *(const f16x8*)&Blds[(wc * 64 + n * 16 + lr) * 32 + lq * 8];
#pragma unroll
        for (int m = 0; m < 4; m++)
#pragma unroll
            for (int n = 0; n < 4; n++)
                acc[m][n] = __builtin_amdgcn_mfma_f32_16x16x32_f16(af[m], bf[n], acc[m][n], 0, 0, 0);
    }

    // epilogue: C frag layout col=lane&15, row=(lane>>4)*4+j
#pragma unroll
    for (int m = 0; m < 4; m++) {
#pragma unroll
        for (int n = 0; n < 4; n++) {
            const int Rb = rBase + wr * 64 + m * 16 + lq * 4;
            const int Cc = cBase + wc * 64 + n * 16 + lr;
#pragma unroll
            for (int j = 0; j < 4; j++) {
                const int R = Rb + j;
                float v = acc[m][n][j] + tb[Cc];
                if constexpr (EPI == EPI_ATT) {
                    outH[(size_t)R * 512 + Cc] = (f16)v;  // BN(z), f16; priors applied later
                } else if constexpr (EPI == EPI_PROJ) {
                    outH[(size_t)R * 256 + Cc] = (f16)v;
                } else if constexpr (EPI == EPI_GLU) {
                    float o = __shfl_xor(v, 1, 64);  // pair val<->gate (interleaved cols)
                    if (!(lane & 1)) {
                        const int xi = Cc >> 1;
                        const size_t id = (size_t)R * 256 + xi;
                        float xn = v * (1.f / (1.f + __expf(-o)));
                        outH[id] = (f16)(xn + (float)xold[id]);
                    }
                } else {  // EPI_OUT
                    outF[(size_t)R * 128 + Cc] = v;
                }
            }
        }
    }
}

// ---------------- sparsemax: one wave per row of 512; z = zbn*priors; masked in-place over zbn ----------------
__global__ __launch_bounds__(256) void sparsemax_kernel(
    const f16* __restrict__ zbn, const float* __restrict__ priors,
    const f16* __restrict__ in16, float* __restrict__ maskout,
    float* __restrict__ npout, f16* __restrict__ masked)
{
    const int w = threadIdx.x >> 6, lane = threadIdx.x & 63;
    const int row = blockIdx.x * 4 + w;
    const size_t base = (size_t)row * 512 + lane * 8;
    f16x8 zv = *(const f16x8*)(zbn + base);
    float4 p0 = *(const float4*)(priors + base);
    float4 p1 = *(const float4*)(priors + base + 4);
    float pr[8] = {p0.x, p0.y, p0.z, p0.w, p1.x, p1.y, p1.z, p1.w};
    float z[8];
#pragma unroll
    for (int j = 0; j < 8; j++) z[j] = (float)zv[j] * pr[j];
    float mx = z[0];
#pragma unroll
    for (int j = 1; j < 8; j++) mx = fmaxf(mx, z[j]);
#pragma unroll
    for (int d = 1; d < 64; d <<= 1) mx = fmaxf(mx, __shfl_xor(mx, d, 64));
    float lo = mx - 1.f, hi = mx;
    for (int it = 0; it < 16; ++it) {
        float tau = 0.5f * (lo + hi);
        float s = 0.f;
#pragma unroll
        for (int j = 0; j < 8; j++) s += fmaxf(z[j] - tau, 0.f);
#pragma unroll
        for (int d = 1; d < 64; d <<= 1) s += __shfl_xor(s, d, 64);
        if (s >= 1.f) lo = tau; else hi = tau;
    }
    float cnt = 0.f, sm = 0.f;
#pragma unroll
    for (int j = 0; j < 8; j++) {
        if (z[j] > lo) { cnt += 1.f; sm += z[j]; }
    }
#pragma unroll
    for (int d = 1; d < 64; d <<= 1) {
        cnt += __shfl_xor(cnt, d, 64);
        sm += __shfl_xor(sm, d, 64);
    }
    const float tau = (sm - 1.f) / cnt;
    f16x8 xv = *(const f16x8*)(in16 + base);
    float mk[8];
#pragma unroll
    for (int j = 0; j < 8; j++) mk[j] = fmaxf(z[j] - tau, 0.f);
    float4 m0 = {mk[0], mk[1], mk[2], mk[3]}, m1 = {mk[4], mk[5], mk[6], mk[7]};
    *(float4*)(maskout + base) = m0;
    *(float4*)(maskout + base + 4) = m1;
    float4 n0 = {pr[0] * (1.f - mk[0]), pr[1] * (1.f - mk[1]), pr[2] * (1.f - mk[2]), pr[3] * (1.f - mk[3])};
    float4 n1 = {pr[4] * (1.f - mk[4]), pr[5] * (1.f - mk[5]), pr[6] * (1.f - mk[6]), pr[7] * (1.f - mk[7])};
    *(float4*)(npout + base) = n0;
    *(float4*)(npout + base + 4) = n1;
    f16x8 mm;
#pragma unroll
    for (int j = 0; j < 8; j++) mm[j] = (f16)(mk[j] * (float)xv[j]);
    *(f16x8*)(masked + base) = mm;  // masked aliases zbn: per-thread read-then-write, safe
}

extern "C" void kernel_launch(void* const* d_in, const int* in_sizes, int n_in,
                              void* d_out, int out_size, void* d_ws, size_t ws_size,
                              hipStream_t stream)
{
    const float* inputs    = (const float*)d_in[0];
    const float* priors    = (const float*)d_in[1];
    const float* att_w     = (const float*)d_in[2];
    const float* att_gamma = (const float*)d_in[3];
    const float* att_beta  = (const float*)d_in[4];
    const float* att_mean  = (const float*)d_in[5];
    const float* att_var   = (const float*)d_in[6];
    const float* proj_w    = (const float*)d_in[7];
    const float* proj_b    = (const float*)d_in[8];
    const float* glu_w     = (const float*)d_in[9];
    const float* glu_gamma = (const float*)d_in[10];
    const float* glu_beta  = (const float*)d_in[11];
    const float* glu_mean  = (const float*)d_in[12];
    const float* glu_var   = (const float*)d_in[13];
    const float* out_w     = (const float*)d_in[14];
    const float* out_b     = (const float*)d_in[15];

    char* ws = (char*)d_ws;
    f16*   watt     = (f16*)(ws + 0);          // 512*512 f16
    f16*   wproj    = (f16*)(ws + 524288);     // 256*512
    f16*   wglu     = (f16*)(ws + 786432);     // 4*512*256
    f16*   wout     = (f16*)(ws + 1835008);    // 128*256
    float* t_att    = (float*)(ws + 1900544);  // 512
    float* t_glu    = (float*)(ws + 1902592);  // 4*512
    f16*   inputs16 = (f16*)(ws + 2097152);    // 65536*512 f16 (64MB)
    f16*   zmask    = (f16*)(ws + 69206016);   // 65536*512 f16: zbn, then masked in-place
    f16*   x0       = (f16*)(ws + 136314880);  // 65536*256 f16
    f16*   x1       = (f16*)(ws + 169869312);  // 65536*256 f16

    float* outp  = (float*)d_out;
    float* maskp = outp + (size_t)65536 * 128;
    float* npp   = maskp + (size_t)65536 * 512;

    prep_kernel<<<2048, 256, 0, stream>>>(inputs, att_w, att_gamma, att_beta, att_mean,
                                          att_var, proj_w, glu_w, glu_gamma, glu_beta,
                                          glu_mean, glu_var, out_w, inputs16,
                                          watt, wproj, wglu, wout, t_att, t_glu);

    // zbn = bn(inputs @ att_w)  (f16, priors NOT applied)
    gemm_kernel<512, 4, EPI_ATT><<<2048, 256, 0, stream>>>(
        inputs16, watt, t_att, nullptr, nullptr, zmask);

    sparsemax_kernel<<<16384, 256, 0, stream>>>(zmask, priors, inputs16, maskp, npp, zmask);

    // x0 = masked @ proj_w + b
    gemm_kernel<512, 2, EPI_PROJ><<<1024, 256, 0, stream>>>(
        zmask, wproj, proj_b, nullptr, nullptr, x0);

    // 4 GLU blocks (interleaved val/gate weights), x ping-pong
    gemm_kernel<256, 4, EPI_GLU><<<2048, 256, 0, stream>>>(
        x0, wglu, t_glu, x0, nullptr, x1);
    gemm_kernel<256, 4, EPI_GLU><<<2048, 256, 0, stream>>>(
        x1, wglu + 131072, t_glu + 512, x1, nullptr, x0);
    gemm_kernel<256, 4, EPI_GLU><<<2048, 256, 0, stream>>>(
        x0, wglu + 262144, t_glu + 1024, x0, nullptr, x1);
    gemm_kernel<256, 4, EPI_GLU><<<2048, 256, 0, stream>>>(
        x1, wglu + 393216, t_glu + 1536, x1, nullptr, x0);

    // output = x @ out_w + b
    gemm_kernel<256, 1, EPI_OUT><<<512, 256, 0, stream>>>(
        x0, wout, out_b, nullptr, outp, nullptr);
}